// Round 12
// baseline (1051.929 us; speedup 1.0000x reference)
//
#include <hip/hip_runtime.h>
#include <hip/hip_cooperative_groups.h>

namespace cg = cooperative_groups;

typedef unsigned short u16;
typedef unsigned char u8;
typedef __attribute__((ext_vector_type(8))) short short8;
typedef __attribute__((ext_vector_type(4))) float f32x4;
typedef __attribute__((ext_vector_type(8))) int int8v;
typedef __attribute__((ext_vector_type(4))) int int4v;

#define LN_EPS 1e-5f
#define SCALE_A 4096.f
#define SCALE_V 8.f
#define INV_SCALE_AV (1.f/32768.f)
#define SCALE_NRM 4.f
#define SCALE_WH 512.f
#define INV_SCALE_H (1.f/2048.f)
#define MX_ONE 0x7F7F7F7Fu

__device__ __forceinline__ u16 f2bf(float f){
    union { float f; unsigned u; } c; c.f = f;
    unsigned u = c.u + 0x7FFFu + ((c.u >> 16) & 1u);
    return (u16)(u >> 16);
}
__device__ __forceinline__ float bf2f(u16 h){
    union { unsigned u; float f; } c; c.u = ((unsigned)h) << 16;
    return c.f;
}
__device__ __forceinline__ u8 f2fp8(float f){
    int r = __builtin_amdgcn_cvt_pk_fp8_f32(f, 0.f, 0, false);
    return (u8)(r & 0xFF);
}
__device__ __forceinline__ u16 f2fp8x2(float a, float b){
    int r = __builtin_amdgcn_cvt_pk_fp8_f32(a, b, 0, false);
    return (u16)(r & 0xFFFF);
}

enum { EPI_NONE=0, EPI_BIAS_RES, EPI_BIAS_RELU, EPI_RELUSQ };
enum { OT_F32=0, OT_BF16=1, OT_FP8=2 };

__device__ __forceinline__ void gl2lds16(const void* g, void* lds){
    __builtin_amdgcn_global_load_lds(
        (const __attribute__((address_space(1))) unsigned*)g,
        (__attribute__((address_space(3))) unsigned*)lds, 16, 0, 0);
}

// ============ bf16 GEMM body (R4 loop: BK=32, single-buffer; trailing sync) ============
template<int EPI, int OT>
__device__ __forceinline__ void bf16_gemm_body(
    u16* sA, u16* sB,
    const u16* Az, const u16* Bz, void* Cv,
    int K, int lda, int ldb, int ldc, size_t zc,
    int m0, int n0,
    const float* bias, const float* ext, int ldext, float scale)
{
    const int tid = threadIdx.x;
    const int lane = tid & 63, quad = lane >> 4, l15 = lane & 15;
    const int wave = tid >> 6;
    const int wm = (wave >> 1) * 64, wn = (wave & 1) * 64;

    const u16* gA[2]; const u16* gB[2]; int lo[2];
#pragma unroll
    for (int r = 0; r < 2; r++){
        const int c = tid + r * 256;
        gA[r] = Az + (size_t)(m0 + (c & 127)) * lda + (c >> 7) * 8;
        gB[r] = Bz + (size_t)(n0 + (c & 127)) * ldb + (c >> 7) * 8;
        lo[r] = ((tid & 192) + r * 256) * 16;
    }

    f32x4 acc[4][4];
#pragma unroll
    for (int i = 0; i < 4; i++)
#pragma unroll
        for (int j = 0; j < 4; j++) acc[i][j] = (f32x4){0.f,0.f,0.f,0.f};

    const u16* fA = sA + quad * 1024 + (wm + l15) * 8;
    const u16* fB = sB + quad * 1024 + (wn + l15) * 8;

    for (int k0 = 0; k0 < K; k0 += 32){
#pragma unroll
        for (int r = 0; r < 2; r++){
            gl2lds16(gA[r] + k0, (char*)sA + lo[r]);
            gl2lds16(gB[r] + k0, (char*)sB + lo[r]);
        }
        __syncthreads();
        short8 a[4], b[4];
#pragma unroll
        for (int t = 0; t < 4; t++){
            a[t] = *(const short8*)(fA + t * 128);
            b[t] = *(const short8*)(fB + t * 128);
        }
#pragma unroll
        for (int i = 0; i < 4; i++)
#pragma unroll
            for (int j = 0; j < 4; j++)
                acc[i][j] = __builtin_amdgcn_mfma_f32_16x16x32_bf16(a[i], b[j], acc[i][j], 0, 0, 0);
        __syncthreads();
    }

    float* Cf = (float*)Cv; u16* Ch = (u16*)Cv; u8* C8 = (u8*)Cv;
#pragma unroll
    for (int i = 0; i < 4; i++){
#pragma unroll
        for (int j = 0; j < 4; j++){
            const int n = n0 + wn + j * 16 + l15;
            float bs = (EPI==EPI_BIAS_RES || EPI==EPI_BIAS_RELU) ? bias[n] : 0.f;
#pragma unroll
            for (int r = 0; r < 4; r++){
                const int m = m0 + wm + i * 16 + quad * 4 + r;
                float v = acc[i][j][r] + bs;
                if (EPI==EPI_BIAS_RES) v += ext[(size_t)m * ldext + n];
                if (EPI==EPI_BIAS_RELU) v = fmaxf(v, 0.f);
                if (EPI==EPI_RELUSQ){ float t = fmaxf(v * scale, 0.f); v = t * t * SCALE_A; }
                if (OT==OT_FP8)       C8[zc + (size_t)m * ldc + n] = f2fp8(v);
                else if (OT==OT_BF16) Ch[zc + (size_t)m * ldc + n] = f2bf(v);
                else                  Cf[zc + (size_t)m * ldc + n] = v;
            }
        }
    }
}

// ============ MX fp8 GEMM body (K=128/MFMA, XOR-swizzled LDS; trailing sync) ============
template<bool VOUT>
__device__ __forceinline__ void mx_gemm_body(
    u8* sA, u8* sB,
    const u8* Az, const u8* Bz, u16* C,
    int K, int lda, int ldb, int ldc, size_t zc,
    int m0, int n0,
    const u16* gate, int ldext, size_t ze,
    const float* bias, u8* vout)
{
    const int tid = threadIdx.x;
    const int lane = tid & 63, quad = lane >> 4, l15 = lane & 15;
    const int wave = tid >> 6;
    const int wm = (wave >> 1) * 64, wn = (wave & 1) * 64;

    const u8* gA[4]; const u8* gB[4]; int lo[4];
#pragma unroll
    for (int p = 0; p < 4; p++){
        const int r = p * 32 + (tid >> 3);
        const int j = (tid & 7) ^ (r & 7);
        gA[p] = Az + (size_t)(m0 + r) * lda + j * 16;
        gB[p] = Bz + (size_t)(n0 + r) * ldb + j * 16;
        lo[p] = p * 4096 + wave * 1024;
    }

    f32x4 acc[4][4];
#pragma unroll
    for (int i = 0; i < 4; i++)
#pragma unroll
        for (int j = 0; j < 4; j++) acc[i][j] = (f32x4){0.f,0.f,0.f,0.f};

    for (int k0 = 0; k0 < K; k0 += 128){
#pragma unroll
        for (int p = 0; p < 4; p++){
            gl2lds16(gA[p] + k0, (char*)sA + lo[p]);
            gl2lds16(gB[p] + k0, (char*)sB + lo[p]);
        }
        __syncthreads();
        int8v a[4], b[4];
#pragma unroll
        for (int i = 0; i < 4; i++){
            const int m = wm + i * 16 + l15;
            const int4v a0 = *(const int4v*)(sA + m * 128 + ((2*quad    ) ^ (m & 7)) * 16);
            const int4v a1 = *(const int4v*)(sA + m * 128 + ((2*quad + 1) ^ (m & 7)) * 16);
            a[i] = (int8v){a0[0],a0[1],a0[2],a0[3],a1[0],a1[1],a1[2],a1[3]};
            const int n = wn + i * 16 + l15;
            const int4v b0 = *(const int4v*)(sB + n * 128 + ((2*quad    ) ^ (n & 7)) * 16);
            const int4v b1 = *(const int4v*)(sB + n * 128 + ((2*quad + 1) ^ (n & 7)) * 16);
            b[i] = (int8v){b0[0],b0[1],b0[2],b0[3],b1[0],b1[1],b1[2],b1[3]};
        }
#pragma unroll
        for (int i = 0; i < 4; i++)
#pragma unroll
            for (int j = 0; j < 4; j++)
                acc[i][j] = __builtin_amdgcn_mfma_scale_f32_16x16x128_f8f6f4(
                    a[i], b[j], acc[i][j], 0, 0, 0, MX_ONE, 0, MX_ONE);
        __syncthreads();
    }

#pragma unroll
    for (int i = 0; i < 4; i++){
#pragma unroll
        for (int j = 0; j < 4; j++){
            const int n = n0 + wn + j * 16 + l15;
#pragma unroll
            for (int r = 0; r < 4; r++){
                const int m = m0 + wm + i * 16 + quad * 4 + r;
                if (VOUT){
                    float h = fmaxf(acc[i][j][r] * INV_SCALE_H + bias[n], 0.f);
                    vout[(size_t)m * 1536 + n] = f2fp8(h * SCALE_V);
                } else {
                    float v = acc[i][j][r] * INV_SCALE_AV
                            * bf2f(gate[ze + (size_t)m * ldext + n]);
                    C[zc + (size_t)m * ldc + n] = f2bf(v);
                }
            }
        }
    }
}

// ---------------- args ----------------
struct MegaArgs {
    const float *x, *Wm, *bm, *g1, *b1, *Wh, *bh, *Wq, *bq, *Wb, *Wo, *bo, *g2, *b2;
    float* out;
    u16 *xbf, *Wmbf; u8* Wh8; u16 *Whgb, *Wqbf, *Wobf, *WbT;
    float* ybuf; u16* wop; u16* n8; u16 *Zb, *ZWbb;
    u8* v8; u16* gbf; u8 *vT8, *A8; u16* Vgbf;
};

// ---------------- per-item device helpers ----------------
__device__ __forceinline__ void cast_item(int i, const MegaArgs& a){
    if (i >= 1736704){
        const int j = i - 1736704;
        if (j < 65536){
            const int e = j >> 8, d = j & 255;
            a.WbT[e * 256 + d] = f2bf(a.Wb[d * 256 + e]);
        }
        return;
    }
    if (i >= 1114112 && i < 1310720){       // Wh v-half -> fp8 * 2^9
        const int off = i - 1114112;
        const float4 v = ((const float4*)a.Wh)[off];
        unsigned r0 = (unsigned)f2fp8x2(v.x * SCALE_WH, v.y * SCALE_WH);
        unsigned r1 = (unsigned)f2fp8x2(v.z * SCALE_WH, v.w * SCALE_WH);
        ((unsigned*)a.Wh8)[off] = r0 | (r1 << 16);
        return;
    }
    const float* src; u16* dst; int off;
    if      (i < 1048576){ src = a.x;  dst = a.xbf;   off = i; }
    else if (i < 1114112){ src = a.Wm; dst = a.Wmbf;  off = i - 1048576; }
    else if (i < 1507328){ src = a.Wh + 786432; dst = a.Whgb; off = i - 1310720; }
    else if (i < 1540096){ src = a.Wq; dst = a.Wqbf;  off = i - 1507328; }
    else                 { src = a.Wo; dst = a.Wobf;  off = i - 1540096; }
    const float4 v = ((const float4*)src)[off];
    ushort4 o; o.x = f2bf(v.x); o.y = f2bf(v.y); o.z = f2bf(v.z); o.w = f2bf(v.w);
    ((ushort4*)dst)[off] = o;
}

__device__ __forceinline__ void tr8_item(int z, int idx, const MegaArgs& a, char* lds){
    const int S = 2048, HID = 1536;
    const int h0 = (idx % 24) * 64, s0 = (idx / 24) * 64;
    u8 (*t)[68] = (u8(*)[68])lds;
    const u8* vb = a.v8 + (size_t)z * S * HID;
    u8* vTb = a.vT8 + (size_t)z * HID * S;
    const int tid = threadIdx.x;
#pragma unroll
    for (int i = 0; i < 4; i++){
        int id2 = tid + i * 256;
        int r = id2 >> 4, c4 = (id2 & 15) * 4;
        uchar4 u = *(const uchar4*)(vb + (size_t)(s0 + r) * HID + h0 + c4);
        t[r][c4] = u.x; t[r][c4+1] = u.y; t[r][c4+2] = u.z; t[r][c4+3] = u.w;
    }
    __syncthreads();
#pragma unroll
    for (int i = 0; i < 4; i++){
        int id2 = tid + i * 256;
        int r = id2 >> 4, c4 = (id2 & 15) * 4;
        uchar4 u;
        u.x = t[c4][r]; u.y = t[c4+1][r]; u.z = t[c4+2][r]; u.w = t[c4+3][r];
        *(uchar4*)(vTb + (size_t)(h0 + r) * S + s0 + c4) = u;
    }
    __syncthreads();   // LDS reuse safety for the next item
}

__device__ __forceinline__ void ln_reduce(float2 v, float* sred, float& mean, float& rstd){
    const int tid = threadIdx.x;
    float s = v.x + v.y, ss = v.x * v.x + v.y * v.y;
#pragma unroll
    for (int off = 32; off > 0; off >>= 1){
        s  += __shfl_down(s,  off);
        ss += __shfl_down(ss, off);
    }
    float* sbuf = sred; float* ssbuf = sred + 8;
    const int wid = tid >> 6, lane = tid & 63;
    if (lane == 0){ sbuf[wid] = s; ssbuf[wid] = ss; }
    __syncthreads();
    if (tid == 0){
        float S = 0.f, SS = 0.f;
#pragma unroll
        for (int i = 0; i < 4; i++){ S += sbuf[i]; SS += ssbuf[i]; }
        const float m = S * (1.f/512.f);
        const float var = SS * (1.f/512.f) - m * m;
        sbuf[4]  = m;
        ssbuf[4] = rsqrtf(var + LN_EPS);
    }
    __syncthreads();
    mean = sbuf[4]; rstd = ssbuf[4];
}

__device__ __forceinline__ void ln1_row(int row, const MegaArgs& a, float* sred){
    const int tid = threadIdx.x;
    __syncthreads();
    const size_t base = (size_t)row * 512 + tid * 2;
    const float2 v = *(const float2*)(a.ybuf + base);
    float mean, rstd;
    ln_reduce(v, sred, mean, rstd);
    const float2 gg = *(const float2*)(a.g1 + tid * 2);
    const float2 bb = *(const float2*)(a.b1 + tid * 2);
    const float ox = (v.x - mean) * rstd * gg.x + bb.x;
    const float oy = (v.y - mean) * rstd * gg.y + bb.y;
    ((unsigned*)a.xbf)[(size_t)row * 256 + tid] =
        ((unsigned)f2bf(oy) << 16) | (unsigned)f2bf(ox);
    a.n8[(size_t)row * 256 + tid] = f2fp8x2(ox * SCALE_NRM, oy * SCALE_NRM);
}

__device__ __forceinline__ void ln2_row(int row, const MegaArgs& a, float* sred){
    const int tid = threadIdx.x;
    __syncthreads();
    const long MD = 4194304;
    const size_t base = (size_t)row * 512 + tid * 2;
    const unsigned p0 = ((const unsigned*)a.wop)[(size_t)row * 256 + tid];
    const unsigned p1 = ((const unsigned*)(a.wop + MD))[(size_t)row * 256 + tid];
    const float2 bb2 = *(const float2*)(a.bo + tid * 2);
    float2 v;
    v.x = bf2f((u16)p0) + bf2f((u16)p1) + bb2.x;
    v.y = bf2f((u16)(p0 >> 16)) + bf2f((u16)(p1 >> 16)) + bb2.y;
    float mean, rstd;
    ln_reduce(v, sred, mean, rstd);
    const float2 gg = *(const float2*)(a.g2 + tid * 2);
    const float2 bb = *(const float2*)(a.b2 + tid * 2);
    const float2 r = *(const float2*)(a.x + base);
    float2 o;
    o.x = (v.x - mean) * rstd * gg.x + bb.x + r.x;
    o.y = (v.y - mean) * rstd * gg.y + bb.y + r.y;
    *(float2*)(a.out + base) = o;
}

// ---------------- the persistent cooperative kernel ----------------
__global__ __launch_bounds__(256, 4)
void mega_k(MegaArgs a)
{
    __shared__ char lds[32768];
    cg::grid_group grid = cg::this_grid();
    const int G = gridDim.x;
    const int bid = blockIdx.x;
    const int tid = threadIdx.x;
    u16* s16 = (u16*)lds;
    u8*  s8  = (u8*)lds;
    float* sred = (float*)lds;
    const int S = 2048, QKD = 256, HID = 1536;
    const long MD = 4194304;

    // P0: casts + Wb transpose
    for (int i = bid * 256 + tid; i < 1802240; i += G * 256) cast_item(i, a);
    grid.sync();

    // P1: y = x@Wm^T + bm + x  (256 tiles, fp32 out)
    for (int t = bid; t < 256; t += G)
        bf16_gemm_body<EPI_BIAS_RES,OT_F32>(s16, s16 + 4096,
            a.xbf, a.Wmbf, a.ybuf, 512, 512, 512, 512, 0,
            (t >> 2) * 128, (t & 3) * 128, a.bm, a.x, 512, 1.f);
    grid.sync();

    // P2: nrm = LN(y) -> bf16 (into xbf) + fp8*4
    for (int r = bid; r < 8192; r += G) ln1_row(r, a, sred);
    grid.sync();

    // P3: dual3 — v fp8 (MX) | gate bf16 | Z bf16   (1664 tiles)
    for (int t = bid; t < 1664; t += G){
        const int bx = t % 26, m0 = (t / 26) * 128;
        if (bx < 12){
            mx_gemm_body<true>(s8, s8 + 16384,
                (const u8*)a.n8, a.Wh8, nullptr,
                512, 512, 512, 0, 0, m0, bx * 128,
                nullptr, 0, 0, a.bh, a.v8);
        } else if (bx < 24){
            bf16_gemm_body<EPI_BIAS_RELU,OT_BF16>(s16, s16 + 4096,
                a.xbf, a.Whgb, a.gbf, 512, 512, 512, 1536, 0,
                m0, (bx - 12) * 128, a.bh + 1536, nullptr, 0, 1.f);
        } else {
            bf16_gemm_body<EPI_BIAS_RELU,OT_BF16>(s16, s16 + 4096,
                a.xbf, a.Wqbf, a.Zb, 512, 512, 512, 256, 0,
                m0, (bx - 24) * 128, a.bq, nullptr, 0, 1.f);
        }
    }
    grid.sync();

    // P4: ZWb = Z @ WbT  (128 tiles)
    for (int t = bid; t < 128; t += G)
        bf16_gemm_body<EPI_NONE,OT_BF16>(s16, s16 + 4096,
            a.Zb, a.WbT, a.ZWbb, 256, 256, 256, 256, 0,
            (t >> 1) * 128, (t & 1) * 128, nullptr, nullptr, 0, 1.f);
    grid.sync();

    // P5: A = relu(ZWb@Z^T/S)^2 * 2^12 -> fp8 (1024 tiles) ; vT = v^T (3072 items)
    for (int t = bid; t < 4096; t += G){
        const int z = t >> 10, bx = t & 1023;
        if (bx < 256){
            bf16_gemm_body<EPI_RELUSQ,OT_FP8>(s16, s16 + 4096,
                a.ZWbb + (size_t)z * S * QKD, a.Zb + (size_t)z * S * QKD, a.A8,
                QKD, QKD, QKD, S, (size_t)z * S * S,
                (bx >> 4) * 128, (bx & 15) * 128,
                nullptr, nullptr, 0, 1.f / (float)S);
        } else {
            tr8_item(z, bx - 256, a, lds);
        }
    }
    grid.sync();

    // P6: Vg = (A @ v) * 2^-15 * gate  (768 tiles, MX K=128)
    for (int t = bid; t < 768; t += G){
        const int z = t / 192, rem = t % 192;
        const int bx = rem % 12, by = rem / 12;
        mx_gemm_body<false>(s8, s8 + 16384,
            a.A8 + (size_t)z * S * S, a.vT8 + (size_t)z * HID * S, a.Vgbf,
            S, S, S, HID, (size_t)z * S * HID,
            by * 128, bx * 128,
            a.gbf, HID, (size_t)z * S * HID, nullptr, nullptr);
    }
    grid.sync();

    // P7: t partials = Vg@Wo^T  (split-K z=2, 512 tiles, bf16 partials)
    for (int t = bid; t < 512; t += G){
        const int z = t >> 8, rem = t & 255;
        bf16_gemm_body<EPI_NONE,OT_BF16>(s16, s16 + 4096,
            a.Vgbf + (size_t)z * 768, a.Wobf + (size_t)z * 768, a.wop,
            768, 1536, 1536, 512, (size_t)z * MD,
            (rem >> 2) * 128, (rem & 3) * 128, nullptr, nullptr, 0, 1.f);
    }
    grid.sync();

    // P8: out = LN(p0+p1+bo) + x
    for (int r = bid; r < 8192; r += G) ln2_row(r, a, sred);
}

extern "C" void kernel_launch(void* const* d_in, const int* in_sizes, int n_in,
                              void* d_out, int out_size, void* d_ws, size_t ws_size,
                              hipStream_t stream)
{
    const int Bn=4, S=2048, D=512, QKD=256, HID=1536;
    const int M = Bn * S;
    const long MD = (long)M * D;
    (void)in_sizes; (void)n_in; (void)out_size; (void)ws_size;

    char* p = (char*)d_ws;
    auto alloc = [&](size_t bytes)->void*{ void* r = p; p += (bytes + 255) & ~(size_t)255; return r; };
    u16*  xbf  = (u16*) alloc((size_t)M*D*2);
    u16*  Wmbf = (u16*) alloc((size_t)D*D*2);
    u8*   Wh8  = (u8*)  alloc((size_t)HID*D);
    u16*  Whgb = (u16*) alloc((size_t)HID*D*2);
    u16*  Wqbf = (u16*) alloc((size_t)QKD*D*2);
    u16*  Wobf = (u16*) alloc((size_t)D*HID*2);
    u16*  WbT  = (u16*) alloc((size_t)QKD*QKD*2);
    float* ybuf= (float*)alloc((size_t)MD*4);
    u16*  wop  = (u16*) alloc((size_t)MD*2*2);
    u16*  n8   = (u16*) alloc((size_t)M*D);
    u16*  Zb   = (u16*) alloc((size_t)M*QKD*2);
    u16*  ZWbb = (u16*) alloc((size_t)M*QKD*2);
    u8*   v8   = (u8*)  alloc((size_t)M*HID);
    u16*  gbf  = (u16*) alloc((size_t)M*HID*2);
    u8*   vT8  = (u8*)  alloc((size_t)M*HID);
    u8*   A8   = (u8*)  alloc((size_t)M*S);
    u16*  Vgbf = (u16*) alloc((size_t)M*HID*2);

    MegaArgs a;
    a.x  = (const float*)d_in[0];  a.Wm = (const float*)d_in[1];
    a.bm = (const float*)d_in[2];  a.g1 = (const float*)d_in[3];
    a.b1 = (const float*)d_in[4];  a.Wh = (const float*)d_in[5];
    a.bh = (const float*)d_in[6];  a.Wq = (const float*)d_in[7];
    a.bq = (const float*)d_in[8];  a.Wb = (const float*)d_in[9];
    a.Wo = (const float*)d_in[10]; a.bo = (const float*)d_in[11];
    a.g2 = (const float*)d_in[12]; a.b2 = (const float*)d_in[13];
    a.out = (float*)d_out;
    a.xbf = xbf; a.Wmbf = Wmbf; a.Wh8 = Wh8; a.Whgb = Whgb;
    a.Wqbf = Wqbf; a.Wobf = Wobf; a.WbT = WbT;
    a.ybuf = ybuf; a.wop = wop; a.n8 = n8; a.Zb = Zb; a.ZWbb = ZWbb;
    a.v8 = v8; a.gbf = gbf; a.vT8 = vT8; a.A8 = A8; a.Vgbf = Vgbf;

    int maxB = 0;
    hipOccupancyMaxActiveBlocksPerMultiprocessor(&maxB, mega_k, 256, 0);
    int G = maxB * 256;               // 256 CUs
    if (G <= 0)   G = 768;            // conservative fallback (3/CU)
    if (G > 2048) G = 2048;

    void* params[] = { (void*)&a };
    hipLaunchCooperativeKernel(mega_k, dim3(G), dim3(256), params, 0, stream);
}

// Round 13
// 743.650 us; speedup vs baseline: 1.4145x; 1.4145x over previous
//
#include <hip/hip_runtime.h>
#include <hip/hip_cooperative_groups.h>

namespace cg = cooperative_groups;

typedef unsigned short u16;
typedef unsigned char u8;
typedef __attribute__((ext_vector_type(8))) short short8;
typedef __attribute__((ext_vector_type(4))) float f32x4;
typedef __attribute__((ext_vector_type(8))) int int8v;
typedef __attribute__((ext_vector_type(4))) int int4v;

#define LN_EPS 1e-5f
#define SCALE_A 4096.f
#define SCALE_V 8.f
#define INV_SCALE_AV (1.f/32768.f)
#define SCALE_NRM 4.f
#define SCALE_WH 512.f
#define INV_SCALE_H (1.f/2048.f)
#define MX_ONE 0x7F7F7F7Fu

__device__ __forceinline__ u16 f2bf(float f){
    union { float f; unsigned u; } c; c.f = f;
    unsigned u = c.u + 0x7FFFu + ((c.u >> 16) & 1u);
    return (u16)(u >> 16);
}
__device__ __forceinline__ float bf2f(u16 h){
    union { unsigned u; float f; } c; c.u = ((unsigned)h) << 16;
    return c.f;
}
__device__ __forceinline__ u8 f2fp8(float f){
    int r = __builtin_amdgcn_cvt_pk_fp8_f32(f, 0.f, 0, false);
    return (u8)(r & 0xFF);
}
__device__ __forceinline__ u16 f2fp8x2(float a, float b){
    int r = __builtin_amdgcn_cvt_pk_fp8_f32(a, b, 0, false);
    return (u16)(r & 0xFFFF);
}

enum { EPI_NONE=0, EPI_BIAS_RES, EPI_BIAS_RELU, EPI_RELUSQ };
enum { OT_F32=0, OT_BF16=1, OT_FP8=2 };

__device__ __forceinline__ void gl2lds16(const void* g, void* lds){
    __builtin_amdgcn_global_load_lds(
        (const __attribute__((address_space(1))) unsigned*)g,
        (__attribute__((address_space(3))) unsigned*)lds, 16, 0, 0);
}

// ============ bf16 GEMM body (R4 loop: BK=32, single-buffer) ============
template<int EPI, int OT>
__device__ __forceinline__ void bf16_gemm_body(
    u16* sA, u16* sB,
    const u16* Az, const u16* Bz, void* Cv,
    int K, int lda, int ldb, int ldc, size_t zc,
    int m0, int n0,
    const float* bias, const float* ext, int ldext, float scale)
{
    const int tid = threadIdx.x;
    const int lane = tid & 63, quad = lane >> 4, l15 = lane & 15;
    const int wave = tid >> 6;
    const int wm = (wave >> 1) * 64, wn = (wave & 1) * 64;

    const u16* gA[2]; const u16* gB[2]; int lo[2];
#pragma unroll
    for (int r = 0; r < 2; r++){
        const int c = tid + r * 256;
        gA[r] = Az + (size_t)(m0 + (c & 127)) * lda + (c >> 7) * 8;
        gB[r] = Bz + (size_t)(n0 + (c & 127)) * ldb + (c >> 7) * 8;
        lo[r] = ((tid & 192) + r * 256) * 16;
    }

    f32x4 acc[4][4];
#pragma unroll
    for (int i = 0; i < 4; i++)
#pragma unroll
        for (int j = 0; j < 4; j++) acc[i][j] = (f32x4){0.f,0.f,0.f,0.f};

    const u16* fA = sA + quad * 1024 + (wm + l15) * 8;
    const u16* fB = sB + quad * 1024 + (wn + l15) * 8;

    for (int k0 = 0; k0 < K; k0 += 32){
#pragma unroll
        for (int r = 0; r < 2; r++){
            gl2lds16(gA[r] + k0, (char*)sA + lo[r]);
            gl2lds16(gB[r] + k0, (char*)sB + lo[r]);
        }
        __syncthreads();
        short8 a[4], b[4];
#pragma unroll
        for (int t = 0; t < 4; t++){
            a[t] = *(const short8*)(fA + t * 128);
            b[t] = *(const short8*)(fB + t * 128);
        }
#pragma unroll
        for (int i = 0; i < 4; i++)
#pragma unroll
            for (int j = 0; j < 4; j++)
                acc[i][j] = __builtin_amdgcn_mfma_f32_16x16x32_bf16(a[i], b[j], acc[i][j], 0, 0, 0);
        __syncthreads();
    }

    float* Cf = (float*)Cv; u16* Ch = (u16*)Cv; u8* C8 = (u8*)Cv;
#pragma unroll
    for (int i = 0; i < 4; i++){
#pragma unroll
        for (int j = 0; j < 4; j++){
            const int n = n0 + wn + j * 16 + l15;
            float bs = (EPI==EPI_BIAS_RES || EPI==EPI_BIAS_RELU) ? bias[n] : 0.f;
#pragma unroll
            for (int r = 0; r < 4; r++){
                const int m = m0 + wm + i * 16 + quad * 4 + r;
                float v = acc[i][j][r] + bs;
                if (EPI==EPI_BIAS_RES) v += ext[(size_t)m * ldext + n];
                if (EPI==EPI_BIAS_RELU) v = fmaxf(v, 0.f);
                if (EPI==EPI_RELUSQ){ float t = fmaxf(v * scale, 0.f); v = t * t * SCALE_A; }
                if (OT==OT_FP8)       C8[zc + (size_t)m * ldc + n] = f2fp8(v);
                else if (OT==OT_BF16) Ch[zc + (size_t)m * ldc + n] = f2bf(v);
                else                  Cf[zc + (size_t)m * ldc + n] = v;
            }
        }
    }
}

// ============ MX fp8 GEMM body (K=128/MFMA, XOR-swizzled LDS) ============
template<bool VOUT>
__device__ __forceinline__ void mx_gemm_body(
    u8* sA, u8* sB,
    const u8* Az, const u8* Bz, u16* C,
    int K, int lda, int ldb, int ldc, size_t zc,
    int m0, int n0,
    const u16* gate, int ldext, size_t ze,
    const float* bias, u8* vout)
{
    const int tid = threadIdx.x;
    const int lane = tid & 63, quad = lane >> 4, l15 = lane & 15;
    const int wave = tid >> 6;
    const int wm = (wave >> 1) * 64, wn = (wave & 1) * 64;

    const u8* gA[4]; const u8* gB[4]; int lo[4];
#pragma unroll
    for (int p = 0; p < 4; p++){
        const int r = p * 32 + (tid >> 3);
        const int j = (tid & 7) ^ (r & 7);
        gA[p] = Az + (size_t)(m0 + r) * lda + j * 16;
        gB[p] = Bz + (size_t)(n0 + r) * ldb + j * 16;
        lo[p] = p * 4096 + wave * 1024;
    }

    f32x4 acc[4][4];
#pragma unroll
    for (int i = 0; i < 4; i++)
#pragma unroll
        for (int j = 0; j < 4; j++) acc[i][j] = (f32x4){0.f,0.f,0.f,0.f};

    for (int k0 = 0; k0 < K; k0 += 128){
#pragma unroll
        for (int p = 0; p < 4; p++){
            gl2lds16(gA[p] + k0, (char*)sA + lo[p]);
            gl2lds16(gB[p] + k0, (char*)sB + lo[p]);
        }
        __syncthreads();
        int8v a[4], b[4];
#pragma unroll
        for (int i = 0; i < 4; i++){
            const int m = wm + i * 16 + l15;
            const int4v a0 = *(const int4v*)(sA + m * 128 + ((2*quad    ) ^ (m & 7)) * 16);
            const int4v a1 = *(const int4v*)(sA + m * 128 + ((2*quad + 1) ^ (m & 7)) * 16);
            a[i] = (int8v){a0[0],a0[1],a0[2],a0[3],a1[0],a1[1],a1[2],a1[3]};
            const int n = wn + i * 16 + l15;
            const int4v b0 = *(const int4v*)(sB + n * 128 + ((2*quad    ) ^ (n & 7)) * 16);
            const int4v b1 = *(const int4v*)(sB + n * 128 + ((2*quad + 1) ^ (n & 7)) * 16);
            b[i] = (int8v){b0[0],b0[1],b0[2],b0[3],b1[0],b1[1],b1[2],b1[3]};
        }
#pragma unroll
        for (int i = 0; i < 4; i++)
#pragma unroll
            for (int j = 0; j < 4; j++)
                acc[i][j] = __builtin_amdgcn_mfma_scale_f32_16x16x128_f8f6f4(
                    a[i], b[j], acc[i][j], 0, 0, 0, MX_ONE, 0, MX_ONE);
        __syncthreads();
    }

#pragma unroll
    for (int i = 0; i < 4; i++){
#pragma unroll
        for (int j = 0; j < 4; j++){
            const int n = n0 + wn + j * 16 + l15;
#pragma unroll
            for (int r = 0; r < 4; r++){
                const int m = m0 + wm + i * 16 + quad * 4 + r;
                if (VOUT){
                    float h = fmaxf(acc[i][j][r] * INV_SCALE_H + bias[n], 0.f);
                    vout[(size_t)m * 1536 + n] = f2fp8(h * SCALE_V);
                } else {
                    float v = acc[i][j][r] * INV_SCALE_AV
                            * bf2f(gate[ze + (size_t)m * ldext + n]);
                    C[zc + (size_t)m * ldc + n] = f2bf(v);
                }
            }
        }
    }
}

// ---------------- args ----------------
struct MegaArgs {
    const float *x, *Wm, *bm, *g1, *b1, *Wh, *bh, *Wq, *bq, *Wb, *Wo, *bo, *g2, *b2;
    float* out;
    u16 *xbf, *Wmbf; u8* Wh8; u16 *Whgb, *Wqbf, *Wobf, *WbT;
    float* ybuf; u16* wop; u16* n8; u16 *Zb, *ZWbb;
    u8* v8; u16* gbf; u8 *vT8, *A8; u16* Vgbf;
};

// ---------------- per-item device helpers ----------------
__device__ __forceinline__ void cast_item(int i, const MegaArgs& a){
    if (i >= 1736704){
        const int j = i - 1736704;
        if (j < 65536){
            const int e = j >> 8, d = j & 255;
            a.WbT[e * 256 + d] = f2bf(a.Wb[d * 256 + e]);
        }
        return;
    }
    if (i >= 1114112 && i < 1310720){       // Wh v-half -> fp8 * 2^9
        const int off = i - 1114112;
        const float4 v = ((const float4*)a.Wh)[off];
        unsigned r0 = (unsigned)f2fp8x2(v.x * SCALE_WH, v.y * SCALE_WH);
        unsigned r1 = (unsigned)f2fp8x2(v.z * SCALE_WH, v.w * SCALE_WH);
        ((unsigned*)a.Wh8)[off] = r0 | (r1 << 16);
        return;
    }
    const float* src; u16* dst; int off;
    if      (i < 1048576){ src = a.x;  dst = a.xbf;   off = i; }
    else if (i < 1114112){ src = a.Wm; dst = a.Wmbf;  off = i - 1048576; }
    else if (i < 1507328){ src = a.Wh + 786432; dst = a.Whgb; off = i - 1310720; }
    else if (i < 1540096){ src = a.Wq; dst = a.Wqbf;  off = i - 1507328; }
    else                 { src = a.Wo; dst = a.Wobf;  off = i - 1540096; }
    const float4 v = ((const float4*)src)[off];
    ushort4 o; o.x = f2bf(v.x); o.y = f2bf(v.y); o.z = f2bf(v.z); o.w = f2bf(v.w);
    ((ushort4*)dst)[off] = o;
}

__device__ __forceinline__ void tr8_item(int z, int idx, const MegaArgs& a, char* lds){
    const int S = 2048, HID = 1536;
    const int h0 = (idx % 24) * 64, s0 = (idx / 24) * 64;
    u8 (*t)[68] = (u8(*)[68])lds;
    const u8* vb = a.v8 + (size_t)z * S * HID;
    u8* vTb = a.vT8 + (size_t)z * HID * S;
    const int tid = threadIdx.x;
#pragma unroll
    for (int i = 0; i < 4; i++){
        int id2 = tid + i * 256;
        int r = id2 >> 4, c4 = (id2 & 15) * 4;
        uchar4 u = *(const uchar4*)(vb + (size_t)(s0 + r) * HID + h0 + c4);
        t[r][c4] = u.x; t[r][c4+1] = u.y; t[r][c4+2] = u.z; t[r][c4+3] = u.w;
    }
    __syncthreads();
#pragma unroll
    for (int i = 0; i < 4; i++){
        int id2 = tid + i * 256;
        int r = id2 >> 4, c4 = (id2 & 15) * 4;
        uchar4 u;
        u.x = t[c4][r]; u.y = t[c4+1][r]; u.z = t[c4+2][r]; u.w = t[c4+3][r];
        *(uchar4*)(vTb + (size_t)(h0 + r) * S + s0 + c4) = u;
    }
    __syncthreads();   // LDS reuse safety for the next item
}

__device__ __forceinline__ void ln_reduce(float2 v, float* sred, float& mean, float& rstd){
    const int tid = threadIdx.x;
    float s = v.x + v.y, ss = v.x * v.x + v.y * v.y;
#pragma unroll
    for (int off = 32; off > 0; off >>= 1){
        s  += __shfl_down(s,  off);
        ss += __shfl_down(ss, off);
    }
    float* sbuf = sred; float* ssbuf = sred + 8;
    const int wid = tid >> 6, lane = tid & 63;
    if (lane == 0){ sbuf[wid] = s; ssbuf[wid] = ss; }
    __syncthreads();
    if (tid == 0){
        float S = 0.f, SS = 0.f;
#pragma unroll
        for (int i = 0; i < 4; i++){ S += sbuf[i]; SS += ssbuf[i]; }
        const float m = S * (1.f/512.f);
        const float var = SS * (1.f/512.f) - m * m;
        sbuf[4]  = m;
        ssbuf[4] = rsqrtf(var + LN_EPS);
    }
    __syncthreads();
    mean = sbuf[4]; rstd = ssbuf[4];
}

__device__ __forceinline__ void ln1_row(int row, const MegaArgs& a, float* sred){
    const int tid = threadIdx.x;
    __syncthreads();
    const size_t base = (size_t)row * 512 + tid * 2;
    const float2 v = *(const float2*)(a.ybuf + base);
    float mean, rstd;
    ln_reduce(v, sred, mean, rstd);
    const float2 gg = *(const float2*)(a.g1 + tid * 2);
    const float2 bb = *(const float2*)(a.b1 + tid * 2);
    const float ox = (v.x - mean) * rstd * gg.x + bb.x;
    const float oy = (v.y - mean) * rstd * gg.y + bb.y;
    ((unsigned*)a.xbf)[(size_t)row * 256 + tid] =
        ((unsigned)f2bf(oy) << 16) | (unsigned)f2bf(ox);
    a.n8[(size_t)row * 256 + tid] = f2fp8x2(ox * SCALE_NRM, oy * SCALE_NRM);
}

__device__ __forceinline__ void ln2_row(int row, const MegaArgs& a, float* sred){
    const int tid = threadIdx.x;
    __syncthreads();
    const long MD = 4194304;
    const size_t base = (size_t)row * 512 + tid * 2;
    const unsigned p0 = ((const unsigned*)a.wop)[(size_t)row * 256 + tid];
    const unsigned p1 = ((const unsigned*)(a.wop + MD))[(size_t)row * 256 + tid];
    const float2 bb2 = *(const float2*)(a.bo + tid * 2);
    float2 v;
    v.x = bf2f((u16)p0) + bf2f((u16)p1) + bb2.x;
    v.y = bf2f((u16)(p0 >> 16)) + bf2f((u16)(p1 >> 16)) + bb2.y;
    float mean, rstd;
    ln_reduce(v, sred, mean, rstd);
    const float2 gg = *(const float2*)(a.g2 + tid * 2);
    const float2 bb = *(const float2*)(a.b2 + tid * 2);
    const float2 r = *(const float2*)(a.x + base);
    float2 o;
    o.x = (v.x - mean) * rstd * gg.x + bb.x + r.x;
    o.y = (v.y - mean) * rstd * gg.y + bb.y + r.y;
    *(float2*)(a.out + base) = o;
}

// ---------------- the persistent cooperative kernel ----------------
// NOTE: no min-waves clamp — R12's __launch_bounds__(256,4) forced VGPR=64 and
// the kernel spilled 1.27 GB to scratch (1052 us). Let the allocator breathe.
__global__ __launch_bounds__(256)
void mega_k(MegaArgs a)
{
    __shared__ char lds[32768];
    cg::grid_group grid = cg::this_grid();
    const int G = gridDim.x;
    const int bid = blockIdx.x;
    const int tid = threadIdx.x;
    u16* s16 = (u16*)lds;
    u8*  s8  = (u8*)lds;
    float* sred = (float*)lds;
    const int S = 2048, QKD = 256, HID = 1536;
    const long MD = 4194304;

    // P0: casts + Wb transpose
    for (int i = bid * 256 + tid; i < 1802240; i += G * 256) cast_item(i, a);
    grid.sync();

    // P1: y = x@Wm^T + bm + x  (256 tiles, fp32 out)
    for (int t = bid; t < 256; t += G)
        bf16_gemm_body<EPI_BIAS_RES,OT_F32>(s16, s16 + 4096,
            a.xbf, a.Wmbf, a.ybuf, 512, 512, 512, 512, 0,
            (t >> 2) * 128, (t & 3) * 128, a.bm, a.x, 512, 1.f);
    grid.sync();

    // P2: nrm = LN(y) -> bf16 (into xbf) + fp8*4
    for (int r = bid; r < 8192; r += G) ln1_row(r, a, sred);
    grid.sync();

    // P3: dual3 — v fp8 (MX) | gate bf16 | Z bf16   (1664 tiles)
    for (int t = bid; t < 1664; t += G){
        const int bx = t % 26, m0 = (t / 26) * 128;
        if (bx < 12){
            mx_gemm_body<true>(s8, s8 + 16384,
                (const u8*)a.n8, a.Wh8, nullptr,
                512, 512, 512, 0, 0, m0, bx * 128,
                nullptr, 0, 0, a.bh, a.v8);
        } else if (bx < 24){
            bf16_gemm_body<EPI_BIAS_RELU,OT_BF16>(s16, s16 + 4096,
                a.xbf, a.Whgb, a.gbf, 512, 512, 512, 1536, 0,
                m0, (bx - 12) * 128, a.bh + 1536, nullptr, 0, 1.f);
        } else {
            bf16_gemm_body<EPI_BIAS_RELU,OT_BF16>(s16, s16 + 4096,
                a.xbf, a.Wqbf, a.Zb, 512, 512, 512, 256, 0,
                m0, (bx - 24) * 128, a.bq, nullptr, 0, 1.f);
        }
    }
    grid.sync();

    // P4: ZWb = Z @ WbT  (128 tiles)
    for (int t = bid; t < 128; t += G)
        bf16_gemm_body<EPI_NONE,OT_BF16>(s16, s16 + 4096,
            a.Zb, a.WbT, a.ZWbb, 256, 256, 256, 256, 0,
            (t >> 1) * 128, (t & 1) * 128, nullptr, nullptr, 0, 1.f);
    grid.sync();

    // P5: A = relu(ZWb@Z^T/S)^2 * 2^12 -> fp8 (1024 tiles) ; vT = v^T (3072 items)
    for (int t = bid; t < 4096; t += G){
        const int z = t >> 10, bx = t & 1023;
        if (bx < 256){
            bf16_gemm_body<EPI_RELUSQ,OT_FP8>(s16, s16 + 4096,
                a.ZWbb + (size_t)z * S * QKD, a.Zb + (size_t)z * S * QKD, a.A8,
                QKD, QKD, QKD, S, (size_t)z * S * S,
                (bx >> 4) * 128, (bx & 15) * 128,
                nullptr, nullptr, 0, 1.f / (float)S);
        } else {
            tr8_item(z, bx - 256, a, lds);
        }
    }
    grid.sync();

    // P6: Vg = (A @ v) * 2^-15 * gate  (768 tiles, MX K=128)
    for (int t = bid; t < 768; t += G){
        const int z = t / 192, rem = t % 192;
        const int bx = rem % 12, by = rem / 12;
        mx_gemm_body<false>(s8, s8 + 16384,
            a.A8 + (size_t)z * S * S, a.vT8 + (size_t)z * HID * S, a.Vgbf,
            S, S, S, HID, (size_t)z * S * HID,
            by * 128, bx * 128,
            a.gbf, HID, (size_t)z * S * HID, nullptr, nullptr);
    }
    grid.sync();

    // P7: t partials = Vg@Wo^T  (split-K z=2, 512 tiles, bf16 partials)
    for (int t = bid; t < 512; t += G){
        const int z = t >> 8, rem = t & 255;
        bf16_gemm_body<EPI_NONE,OT_BF16>(s16, s16 + 4096,
            a.Vgbf + (size_t)z * 768, a.Wobf + (size_t)z * 768, a.wop,
            768, 1536, 1536, 512, (size_t)z * MD,
            (rem >> 2) * 128, (rem & 3) * 128, nullptr, nullptr, 0, 1.f);
    }
    grid.sync();

    // P8: out = LN(p0+p1+bo) + x
    for (int r = bid; r < 8192; r += G) ln2_row(r, a, sred);
}

extern "C" void kernel_launch(void* const* d_in, const int* in_sizes, int n_in,
                              void* d_out, int out_size, void* d_ws, size_t ws_size,
                              hipStream_t stream)
{
    const int Bn=4, S=2048, D=512, QKD=256, HID=1536;
    const int M = Bn * S;
    const long MD = (long)M * D;
    (void)in_sizes; (void)n_in; (void)out_size; (void)ws_size;

    char* p = (char*)d_ws;
    auto alloc = [&](size_t bytes)->void*{ void* r = p; p += (bytes + 255) & ~(size_t)255; return r; };
    u16*  xbf  = (u16*) alloc((size_t)M*D*2);
    u16*  Wmbf = (u16*) alloc((size_t)D*D*2);
    u8*   Wh8  = (u8*)  alloc((size_t)HID*D);
    u16*  Whgb = (u16*) alloc((size_t)HID*D*2);
    u16*  Wqbf = (u16*) alloc((size_t)QKD*D*2);
    u16*  Wobf = (u16*) alloc((size_t)D*HID*2);
    u16*  WbT  = (u16*) alloc((size_t)QKD*QKD*2);
    float* ybuf= (float*)alloc((size_t)MD*4);
    u16*  wop  = (u16*) alloc((size_t)MD*2*2);
    u16*  n8   = (u16*) alloc((size_t)M*D);
    u16*  Zb   = (u16*) alloc((size_t)M*QKD*2);
    u16*  ZWbb = (u16*) alloc((size_t)M*QKD*2);
    u8*   v8   = (u8*)  alloc((size_t)M*HID);
    u16*  gbf  = (u16*) alloc((size_t)M*HID*2);
    u8*   vT8  = (u8*)  alloc((size_t)M*HID);
    u8*   A8   = (u8*)  alloc((size_t)M*S);
    u16*  Vgbf = (u16*) alloc((size_t)M*HID*2);

    MegaArgs a;
    a.x  = (const float*)d_in[0];  a.Wm = (const float*)d_in[1];
    a.bm = (const float*)d_in[2];  a.g1 = (const float*)d_in[3];
    a.b1 = (const float*)d_in[4];  a.Wh = (const float*)d_in[5];
    a.bh = (const float*)d_in[6];  a.Wq = (const float*)d_in[7];
    a.bq = (const float*)d_in[8];  a.Wb = (const float*)d_in[9];
    a.Wo = (const float*)d_in[10]; a.bo = (const float*)d_in[11];
    a.g2 = (const float*)d_in[12]; a.b2 = (const float*)d_in[13];
    a.out = (float*)d_out;
    a.xbf = xbf; a.Wmbf = Wmbf; a.Wh8 = Wh8; a.Whgb = Whgb;
    a.Wqbf = Wqbf; a.Wobf = Wobf; a.WbT = WbT;
    a.ybuf = ybuf; a.wop = wop; a.n8 = n8; a.Zb = Zb; a.ZWbb = ZWbb;
    a.v8 = v8; a.gbf = gbf; a.vT8 = vT8; a.A8 = A8; a.Vgbf = Vgbf;

    int maxB = 0;
    hipOccupancyMaxActiveBlocksPerMultiprocessor(&maxB, mega_k, 256, 0);
    int G = maxB * 256;               // 256 CUs
    if (G <= 0)   G = 512;            // conservative fallback (2/CU)
    if (G > 2048) G = 2048;

    void* params[] = { (void*)&a };
    hipLaunchCooperativeKernel(mega_k, dim3(G), dim3(256), params, 0, stream);
}